// Round 1
// baseline (402.108 us; speedup 1.0000x reference)
//
#include <hip/hip_runtime.h>
#include <hip/hip_bf16.h>

#define IN_DIM 128
#define OUT_DIM 64

// K1: one wave (64 lanes) per node. lane = output dim d.
// Computes Wh[n][d] = sum_k h[n][k]*W[k][d] + Wb[d], plus the two node-level
// attention partial scores a_dst[n] = Wh[n].dot(Aw[:64]), a_src[n] = Wh[n].dot(Aw[64:]).
__global__ __launch_bounds__(256) void gat_proj(
    const float* __restrict__ h, const float* __restrict__ W,
    const float* __restrict__ Wb, const float* __restrict__ Aw,
    float* __restrict__ Wh, float* __restrict__ a_dst_arr,
    float* __restrict__ a_src_arr, int N)
{
    int wave = (int)((blockIdx.x * blockDim.x + threadIdx.x) >> 6);
    int lane = threadIdx.x & 63;
    if (wave >= N) return;

    const float* hr = h + (size_t)wave * IN_DIM;
    float acc = Wb[lane];
    #pragma unroll 4
    for (int k = 0; k < IN_DIM; k += 4) {
        float4 h4 = *(const float4*)(hr + k);   // broadcast load (all lanes same addr)
        acc += h4.x * W[(k + 0) * OUT_DIM + lane];
        acc += h4.y * W[(k + 1) * OUT_DIM + lane];
        acc += h4.z * W[(k + 2) * OUT_DIM + lane];
        acc += h4.w * W[(k + 3) * OUT_DIM + lane];
    }
    Wh[(size_t)wave * OUT_DIM + lane] = acc;

    // Wave-reduce the two attention partials.
    float pd = acc * Aw[lane];            // contribution to a_dst (A_w[:64])
    float ps = acc * Aw[OUT_DIM + lane];  // contribution to a_src (A_w[64:])
    #pragma unroll
    for (int off = 32; off > 0; off >>= 1) {
        pd += __shfl_down(pd, off);
        ps += __shfl_down(ps, off);
    }
    if (lane == 0) {
        a_dst_arr[wave] = pd;
        a_src_arr[wave] = ps;
    }
}

// K2: one thread per edge. e = leaky_relu(a_dst[dst]+a_src[src]+Ab), ex = exp(e),
// den[dst] += ex. (Max-subtraction omitted: alpha is invariant and e is small.)
__global__ __launch_bounds__(256) void gat_edge(
    const int* __restrict__ src, const int* __restrict__ dst,
    const float* __restrict__ a_dst_arr, const float* __restrict__ a_src_arr,
    const float* __restrict__ Ab,
    float* __restrict__ ex, float* __restrict__ den, int E)
{
    int e = (int)(blockIdx.x * blockDim.x + threadIdx.x);
    if (e >= E) return;
    int s = src[e];
    int t = dst[e];
    float v = a_dst_arr[t] + a_src_arr[s] + Ab[0];
    v = (v > 0.0f) ? v : 0.2f * v;   // leaky_relu slope 0.2
    float x = expf(v);
    ex[e] = x;
    atomicAdd(&den[t], x);
}

// K3: one wave per edge, lane = dim. out[dst][d] += (ex[e]/den[dst]) * Wh[src][d].
__global__ __launch_bounds__(256) void gat_agg(
    const int* __restrict__ src, const int* __restrict__ dst,
    const float* __restrict__ ex, const float* __restrict__ den,
    const float* __restrict__ Wh, float* __restrict__ out, int E)
{
    int e = (int)((blockIdx.x * blockDim.x + threadIdx.x) >> 6);
    int lane = threadIdx.x & 63;
    if (e >= E) return;
    int s = src[e];
    int t = dst[e];
    float alpha = ex[e] / den[t];
    float v = alpha * Wh[(size_t)s * OUT_DIM + lane];
    atomicAdd(out + (size_t)t * OUT_DIM + lane, v);
}

extern "C" void kernel_launch(void* const* d_in, const int* in_sizes, int n_in,
                              void* d_out, int out_size, void* d_ws, size_t ws_size,
                              hipStream_t stream)
{
    const float* h   = (const float*)d_in[0];
    const float* W_w = (const float*)d_in[1];
    const float* W_b = (const float*)d_in[2];
    const float* A_w = (const float*)d_in[3];
    const float* A_b = (const float*)d_in[4];
    const int*   src = (const int*)d_in[5];
    const int*   dst = (const int*)d_in[6];
    float* out = (float*)d_out;

    const int N = in_sizes[0] / IN_DIM;   // 50000
    const int E = in_sizes[5];            // 800000

    // Workspace layout (floats): Wh[N*64] | a_dst[N] | a_src[N] | den[N] | ex[E]
    float* ws      = (float*)d_ws;
    float* Wh      = ws;
    float* a_dst_a = Wh + (size_t)N * OUT_DIM;
    float* a_src_a = a_dst_a + N;
    float* den     = a_src_a + N;
    float* ex      = den + N;

    // Zero the accumulation targets (d_out / d_ws are poisoned before each call).
    hipMemsetAsync(out, 0, (size_t)out_size * sizeof(float), stream);
    hipMemsetAsync(den, 0, (size_t)N * sizeof(float), stream);

    // K1: projection + attention partials. One wave per node.
    {
        int waves_per_block = 256 / 64;
        int grid = (N + waves_per_block - 1) / waves_per_block;
        gat_proj<<<grid, 256, 0, stream>>>(h, W_w, W_b, A_w, Wh, a_dst_a, a_src_a, N);
    }

    // K2: edge logits + denominator accumulation.
    {
        int grid = (E + 255) / 256;
        gat_edge<<<grid, 256, 0, stream>>>(src, dst, a_dst_a, a_src_a, A_b, ex, den, E);
    }

    // K3: weighted scatter-aggregate. One wave per edge.
    {
        int waves_per_block = 256 / 64;
        int grid = (E + waves_per_block - 1) / waves_per_block;
        gat_agg<<<grid, 256, 0, stream>>>(src, dst, ex, den, Wh, out, E);
    }
}